// Round 7
// baseline (130.877 us; speedup 1.0000x reference)
//
#include <hip/hip_runtime.h>
#include <hip/hip_bf16.h>
#include <cstdint>

// Problem constants (fixed by setup_inputs)
#define B_    32
#define T_    4096
#define C_    256
#define BM    64     // time rows per block
#define DMAX  16     // max supported dilation (problem uses 4)
#define NROWS (BM + DMAX)

typedef __attribute__((ext_vector_type(8))) short bf16x8;
typedef __attribute__((ext_vector_type(4))) float f32x4;
typedef __attribute__((ext_vector_type(4))) short s16x4;

static __device__ __forceinline__ short f2bf(float f) {
  __hip_bfloat16 h = __float2bfloat16(f);
  union { __hip_bfloat16 h; short s; } u; u.h = h;
  return u.s;
}

static __device__ __forceinline__ float rcp_(float x) {
  return __builtin_amdgcn_rcpf(x);
}

// ---------------------------------------------------------------------------
// Prep: bf16 weight image, LINEAR layout for direct per-lane fragment loads:
//   wimg[((nb*16 + ks)*256 + np)*32 + kk]   (shorts)
// nb = N-half, ks = k-step (K=32), np = local col (0..127 value, 128..255
// gate), kk = k within step. k = 32*ks + kk: k<256 -> tap0, else tap1.
// ---------------------------------------------------------------------------
__global__ void prep_weights(const float* __restrict__ Wv, const float* __restrict__ Wg,
                             const float* __restrict__ bv, const float* __restrict__ bg,
                             short* __restrict__ wimg, float* __restrict__ bcat) {
  int id = blockIdx.x * 256 + threadIdx.x;   // 2*16*256*32 = 262144 total
  int kk = id & 31;
  int np = (id >> 5) & 255;
  int ks = (id >> 13) & 15;
  int nb = id >> 17;
  int k = ks * 32 + kk, tap = k >> 8, kr = k & 255;
  int sel = np >> 7;
  int f = nb * 128 + (np & 127);
  const float* W = sel ? Wg : Wv;
  wimg[id] = f2bf(W[((size_t)tap * 256 + kr) * 256 + f]);
  if (id < 512) bcat[id] = (id < 256) ? bv[id] : bg[id - 256];
}

// ---------------------------------------------------------------------------
// Main: 256 threads = 4 waves. Block = 64 time rows x one N-half. LDS = 40 KiB
// x-tile only -> 4 blocks/CU. K-loop reordered into 8 channel-block iterations
// x 2 taps (both taps of a channel block share LDS columns); x staging for
// block c+1 is PIPELINED into block c's compute (loads->regs before MFMAs,
// cvt+LDS-write after). One barrier per iteration, no double buffer (disjoint
// LDS columns). Transposed MFMA -> float4 nt-stores.
// ---------------------------------------------------------------------------
__global__ __launch_bounds__(256, 4) void snail_main(
    const float* __restrict__ x, const short* __restrict__ wimg,
    const float* __restrict__ bcat, const int* __restrict__ dptr,
    float* __restrict__ out) {
  __shared__ __align__(16) short lx[NROWS * C_];   // 40 KiB, swizzled bf16 x-tile

  const int d = *dptr;
  // XCD-aware bijective swizzle (4096 blocks, 4096 % 8 == 0)
  const int bid = blockIdx.x;
  const int swz = (bid & 7) * 512 + (bid >> 3);
  const int nb = swz & 1;                 // N-half
  const int t0 = ((swz >> 1) & 63) * BM;  // time tile
  const int b  = swz >> 7;                // batch

  const int tid  = threadIdx.x;
  const int lane = tid & 63;
  const int w    = tid >> 6;
  const int row15 = lane & 15;
  const int qw    = lane >> 4;

  const float* xb = x + (size_t)b * T_ * C_;
  float* ob = out + (size_t)b * T_ * 512;

  const int nrows = BM + d;               // valid LDS rows

  // Channel-block staging: block c covers c4 units [8c, 8c+8) (32 channels),
  // all nrows rows. 3 predicated f32x4 loads per thread.
  f32x4 sreg[3];

#define STAGE_LOAD(CB) do {                                             \
    _Pragma("unroll")                                                   \
    for (int j = 0; j < 3; ++j) {                                       \
      int idx = j * 256 + tid;                                          \
      int r_ = idx >> 3, c4_ = (CB) * 8 + (idx & 7);                    \
      int t_ = t0 - d + r_;                                             \
      sreg[j] = (f32x4){0.f, 0.f, 0.f, 0.f};                            \
      if (r_ < nrows && t_ >= 0)                                        \
        sreg[j] = *(const f32x4*)(xb + (size_t)t_ * C_ + c4_ * 4);      \
    }                                                                   \
  } while (0)

#define STAGE_WRITE(CB) do {                                            \
    _Pragma("unroll")                                                   \
    for (int j = 0; j < 3; ++j) {                                       \
      int idx = j * 256 + tid;                                          \
      int r_ = idx >> 3, c4_ = (CB) * 8 + (idx & 7);                    \
      int t_ = t0 - d + r_;                                             \
      if (r_ < nrows) {                                                 \
        if (r_ >= d && ((CB) >> 2) == nb)                               \
          __builtin_nontemporal_store(sreg[j],                          \
              (f32x4*)(ob + (size_t)t_ * 512 + C_ + c4_ * 4));          \
        s16x4 s_;                                                       \
        s_.x = f2bf(sreg[j].x); s_.y = f2bf(sreg[j].y);                 \
        s_.z = f2bf(sreg[j].z); s_.w = f2bf(sreg[j].w);                 \
        int byte_ = (r_ * 512 + c4_ * 8) ^ ((r_ & 7) << 4);             \
        *(s16x4*)((char*)lx + byte_) = s_;                              \
      }                                                                 \
    }                                                                   \
  } while (0)

  f32x4 accv[4][2], accg[4][2];
#pragma unroll
  for (int mi = 0; mi < 4; ++mi)
#pragma unroll
    for (int ni = 0; ni < 2; ++ni) {
      accv[mi][ni] = (f32x4){0.f, 0.f, 0.f, 0.f};
      accg[mi][ni] = (f32x4){0.f, 0.f, 0.f, 0.f};
    }

  // per-lane weight base: np = w*32 + row15 (value), kk = qw*8
  const short* wl = wimg + (size_t)nb * 131072 + (w * 32 + row15) * 32 + qw * 8;

#define STEP(KS) do {                                                   \
    const short* wk_ = wl + (KS) * 8192;                                \
    bf16x8 w0 = *(const bf16x8*)(wk_);                                  \
    bf16x8 w1 = *(const bf16x8*)(wk_ + 512);                            \
    bf16x8 w2 = *(const bf16x8*)(wk_ + 4096);                           \
    bf16x8 w3 = *(const bf16x8*)(wk_ + 4608);                           \
    bf16x8 af[4];                                                       \
    const int rofs_ = ((KS) >= 8) ? d : 0;                              \
    const int cb_ = ((KS) & 7) * 64 + qw * 16;                          \
    _Pragma("unroll")                                                   \
    for (int mi = 0; mi < 4; ++mi) {                                    \
      int r_ = 16 * mi + row15 + rofs_;                                 \
      af[mi] = *(const bf16x8*)((const char*)lx +                       \
               ((r_ * 512 + cb_) ^ ((r_ & 7) << 4)));                   \
    }                                                                   \
    _Pragma("unroll")                                                   \
    for (int mi = 0; mi < 4; ++mi) {                                    \
      accv[mi][0] = __builtin_amdgcn_mfma_f32_16x16x32_bf16(w0, af[mi], accv[mi][0], 0, 0, 0); \
      accv[mi][1] = __builtin_amdgcn_mfma_f32_16x16x32_bf16(w1, af[mi], accv[mi][1], 0, 0, 0); \
      accg[mi][0] = __builtin_amdgcn_mfma_f32_16x16x32_bf16(w2, af[mi], accg[mi][0], 0, 0, 0); \
      accg[mi][1] = __builtin_amdgcn_mfma_f32_16x16x32_bf16(w3, af[mi], accg[mi][1], 0, 0, 0); \
    }                                                                   \
  } while (0)

  // ---- prologue: stage channel block 0 only
  STAGE_LOAD(0);
  STAGE_WRITE(0);
  __syncthreads();

  // ---- pipelined main loop: compute block c (taps 0+1) while staging c+1
#pragma unroll 1
  for (int c = 0; c < 8; ++c) {
    if (c < 7) STAGE_LOAD(c + 1);   // loads in flight during both STEPs
    STEP(c);                        // tap0: ks = c
    STEP(c + 8);                    // tap1: ks = c + 8 (rows shifted by d)
    if (c < 7) STAGE_WRITE(c + 1);  // loads have had 2 STEPs to land
    __syncthreads();                // writes to block c+1 visible next iter
  }
#undef STEP
#undef STAGE_LOAD
#undef STAGE_WRITE

  // ---- epilogue: out[t][f] = tanh(v+bv)*sigmoid(g+bg), float4 nt-stores
  //      D^T layout: t = t0+16mi+row15 ; f = nb*128 + w*32 + 16ni + qw*4 + j
#pragma unroll
  for (int ni = 0; ni < 2; ++ni) {
    int f0 = nb * 128 + w * 32 + 16 * ni + qw * 4;
    f32x4 bv4 = *(const f32x4*)(bcat + f0);
    f32x4 bg4 = *(const f32x4*)(bcat + 256 + f0);
#pragma unroll
    for (int mi = 0; mi < 4; ++mi) {
      int t = t0 + 16 * mi + row15;
      f32x4 v = accv[mi][ni], g = accg[mi][ni];
      f32x4 res;
#pragma unroll
      for (int j = 0; j < 4; ++j) {
        float vv = v[j] + bv4[j], gg = g[j] + bg4[j];
        float th = 1.f - 2.f * rcp_(__expf(2.f * vv) + 1.f);
        float sg = rcp_(1.f + __expf(-gg));
        res[j] = th * sg;
      }
      __builtin_nontemporal_store(res, (f32x4*)(ob + (size_t)t * 512 + f0));
    }
  }
}

extern "C" void kernel_launch(void* const* d_in, const int* in_sizes, int n_in,
                              void* d_out, int out_size, void* d_ws, size_t ws_size,
                              hipStream_t stream) {
  const float* x  = (const float*)d_in[0];
  const float* Wv = (const float*)d_in[1];
  const float* bv = (const float*)d_in[2];
  const float* Wg = (const float*)d_in[3];
  const float* bg = (const float*)d_in[4];
  const int* dil  = (const int*)d_in[5];
  float* out = (float*)d_out;

  short* wimg = (short*)d_ws;                          // 512 KiB weight image
  float* bcat = (float*)((char*)d_ws + 16 * 32768);    // 2 KiB biases

  prep_weights<<<1024, 256, 0, stream>>>(Wv, Wg, bv, bg, wimg, bcat);
  snail_main<<<B_ * (T_ / BM) * 2, 256, 0, stream>>>(x, wimg, bcat, dil, out);
}